// Round 3
// baseline (715.575 us; speedup 1.0000x reference)
//
#include <hip/hip_runtime.h>

#define NROWS 8192  // BT * N = 8 * 1024

// ---------------------------------------------------------------------------
// K1: LayerNorm over D=256 + transpose to K-major xnT[d][bt*1024+n]
// ---------------------------------------------------------------------------
__global__ __launch_bounds__(256) void ln_kernel(const float* __restrict__ x,
                                                 const float* __restrict__ gamma,
                                                 const float* __restrict__ beta,
                                                 float* __restrict__ xnT) {
  __shared__ float red[2][4][64];
  const int blk = blockIdx.x;  // 128 = bt(8) x nchunk(16)
  const int bt = blk >> 4;
  const int b = bt >> 2, t = bt & 3;
  const int n0 = (blk & 15) << 6;
  const int part = threadIdx.x >> 6, r = threadIdx.x & 63;
  const int n = n0 + r;
  const float* xp = x + ((size_t)(b * 256) * 4 + t) * 1024 + n;  // d stride 4096
  float sum = 0.f, sumsq = 0.f;
#pragma unroll 8
  for (int dd = 0; dd < 64; ++dd) {
    float vv = xp[(size_t)(part * 64 + dd) * 4096];
    sum += vv;
    sumsq += vv * vv;
  }
  red[0][part][r] = sum;
  red[1][part][r] = sumsq;
  __syncthreads();
  const float s1 = red[0][0][r] + red[0][1][r] + red[0][2][r] + red[0][3][r];
  const float s2 = red[1][0][r] + red[1][1][r] + red[1][2][r] + red[1][3][r];
  const float mu = s1 * (1.0f / 256.0f);
  const float var = s2 * (1.0f / 256.0f) - mu * mu;
  const float rstd = rsqrtf(var + 1e-6f);
  float* outp = xnT + (size_t)bt * 1024 + n;
#pragma unroll 8
  for (int dd = 0; dd < 64; ++dd) {
    const int d = part * 64 + dd;
    float vv = xp[(size_t)d * 4096];
    outp[(size_t)d * NROWS] = (vv - mu) * rstd * gamma[d] + beta[d];
  }
}

// ---------------------------------------------------------------------------
// K2: 5 projections fused via grid.z. C[m][o] = sum_d xnT[d][m] * W[o][d].
// ---------------------------------------------------------------------------
__global__ __launch_bounds__(256) void proj_kernel(
    const float* __restrict__ xnT,
    const float* __restrict__ Wq, const float* __restrict__ Wk,
    const float* __restrict__ Wv, const float* __restrict__ Wkl,
    const float* __restrict__ Wvl, const float* __restrict__ qb,
    float* __restrict__ qo, float* __restrict__ ko, float* __restrict__ vo,
    float* __restrict__ klo, float* __restrict__ vlo) {
  __shared__ float As[16][64];
  __shared__ float Bs[16][68];
  const int z = blockIdx.z;
  const float* Wm = (z == 0) ? Wq : (z == 1) ? Wk : (z == 2) ? Wv : (z == 3) ? Wkl : Wvl;
  float* Cm = (z == 0) ? qo : (z == 1) ? ko : (z == 2) ? vo : (z == 3) ? klo : vlo;
  const int m0 = blockIdx.x * 64;
  const int o0 = blockIdx.y * 64;
  const int tid = threadIdx.x;
  const int tx = tid & 15, ty = tid >> 4;
  float c[4][4] = {};
#pragma unroll 1
  for (int k0 = 0; k0 < 256; k0 += 16) {
    const int ml = tid & 63, kl4 = tid >> 6;
#pragma unroll
    for (int r = 0; r < 4; ++r)
      As[kl4 + r * 4][ml] = xnT[(size_t)(k0 + kl4 + r * 4) * NROWS + m0 + ml];
    const int kb = tid & 15, ob = tid >> 4;
#pragma unroll
    for (int r = 0; r < 4; ++r)
      Bs[kb][ob + r * 16] = Wm[(size_t)(o0 + ob + r * 16) * 256 + k0 + kb];
    __syncthreads();
#pragma unroll
    for (int kk = 0; kk < 16; ++kk) {
      const float4 a4 = *(const float4*)&As[kk][tx * 4];
      const float4 b4 = *(const float4*)&Bs[kk][ty * 4];
      const float a[4] = {a4.x, a4.y, a4.z, a4.w};
      const float b[4] = {b4.x, b4.y, b4.z, b4.w};
#pragma unroll
      for (int i = 0; i < 4; ++i)
#pragma unroll
        for (int j = 0; j < 4; ++j) c[i][j] += a[i] * b[j];
    }
    __syncthreads();
  }
#pragma unroll
  for (int i = 0; i < 4; ++i) {
    const int m = m0 + tx * 4 + i;
    const int bt = m >> 10, n = m & 1023;
#pragma unroll
    for (int j = 0; j < 4; ++j) {
      const int o = o0 + ty * 4 + j;
      float val = c[i][j];
      if (z == 0) val += qb[o];
      Cm[((size_t)(bt * 8 + (o >> 5)) * 1024 + n) * 32 + (o & 31)] = val;
    }
  }
}

// ---------------------------------------------------------------------------
// K3: flash attention, split-K across 4 waves. K/V rows are WAVE-UNIFORM in
// the split-K scheme -> fetched via the scalar pipe (s_load into SGPRs, FMAs
// read the SGPR operand directly). No LDS staging, no barriers in main loop.
// LDS used only for the final 4-way online-softmax merge.
// ---------------------------------------------------------------------------
#define CH 16  // keys per softmax chunk (fully unrolled: s[] must stay in regs)
__global__ __launch_bounds__(256) void attn_kernel(
    const float* __restrict__ q, const float* __restrict__ k,
    const float* __restrict__ v, const float* __restrict__ klp,
    const float* __restrict__ vlp, float* __restrict__ ctx) {
  __shared__ float smem[8960];  // merge buffer: 4 waves * 64 lanes * 35 floats
  const int qt = blockIdx.x;    // 16 query tiles
  const int bth = blockIdx.y;   // 64 = bt*8+head
  const int tid = threadIdx.x;
  const int w = __builtin_amdgcn_readfirstlane(tid >> 6);  // force SGPR/uniform
  const int lane = tid & 63;
  const int n = qt * 64 + lane;
  const float SCALE = 0.17677669529663687f * 1.4426950408889634f;  // dh^-.5 * log2e

  float qr[32];
  {
    const float4* qp = (const float4*)(q + ((size_t)bth * 1024 + n) * 32);
#pragma unroll
    for (int f = 0; f < 8; ++f) {
      float4 tq = qp[f];
      qr[f * 4 + 0] = tq.x * SCALE; qr[f * 4 + 1] = tq.y * SCALE;
      qr[f * 4 + 2] = tq.z * SCALE; qr[f * 4 + 3] = tq.w * SCALE;
    }
  }
  float acc[32];
#pragma unroll
  for (int d = 0; d < 32; ++d) acc[d] = 0.f;
  float mloc = -1e30f, lloc = 0.f;

  const size_t kvbase = (size_t)bth * 1024;
  const float* kw = k + (kvbase + (size_t)w * 256) * 32;  // wave-uniform base
  const float* vw = v + (kvbase + (size_t)w * 256) * 32;

#pragma unroll 1
  for (int t = 0; t < 256 / CH; ++t) {
    float s[CH];
#pragma unroll
    for (int j = 0; j < CH; ++j) {
      const float* kr = kw + (size_t)(t * CH + j) * 32;  // uniform -> s_load
      float s0 = 0.f, s1 = 0.f, s2 = 0.f, s3 = 0.f;
#pragma unroll
      for (int d = 0; d < 32; d += 4) {
        s0 = fmaf(qr[d + 0], kr[d + 0], s0);
        s1 = fmaf(qr[d + 1], kr[d + 1], s1);
        s2 = fmaf(qr[d + 2], kr[d + 2], s2);
        s3 = fmaf(qr[d + 3], kr[d + 3], s3);
      }
      s[j] = (s0 + s1) + (s2 + s3);
    }
    float tm = s[0];
#pragma unroll
    for (int j = 1; j < CH; ++j) tm = fmaxf(tm, s[j]);
    const float mnew = fmaxf(mloc, tm);
    const float alpha = __builtin_amdgcn_exp2f(mloc - mnew);
    mloc = mnew;
    lloc *= alpha;
#pragma unroll
    for (int d = 0; d < 32; ++d) acc[d] *= alpha;
#pragma unroll
    for (int j = 0; j < CH; ++j) {
      const float p = __builtin_amdgcn_exp2f(s[j] - mnew);
      lloc += p;
      const float* vr = vw + (size_t)(t * CH + j) * 32;  // uniform -> s_load
#pragma unroll
      for (int d = 0; d < 32; ++d) acc[d] = fmaf(p, vr[d], acc[d]);
    }
  }

  // wave 3: local 3x3 neighborhood as one extra masked tile (per-lane gather)
  if (w == 3) {
    const int pi = n >> 5, pj = n & 31;
    float sl[9];
#pragma unroll
    for (int tt = 0; tt < 9; ++tt) {
      const int ni = pi + tt / 3 - 1;
      const int nj = pj + tt % 3 - 1;
      const bool ok = (ni >= 0) && (ni < 32) && (nj >= 0) && (nj < 32);
      float s = -1e30f;
      if (ok) {
        const float4* kr = (const float4*)(klp + (kvbase + ni * 32 + nj) * 32);
        float s0 = 0.f, s1 = 0.f, s2 = 0.f, s3 = 0.f;
#pragma unroll
        for (int f = 0; f < 8; f += 4) {
          float4 k0 = kr[f], k1 = kr[f + 1], k2 = kr[f + 2], k3 = kr[f + 3];
          s0 += qr[f * 4 + 0] * k0.x + qr[f * 4 + 1] * k0.y + qr[f * 4 + 2] * k0.z + qr[f * 4 + 3] * k0.w;
          s1 += qr[f * 4 + 4] * k1.x + qr[f * 4 + 5] * k1.y + qr[f * 4 + 6] * k1.z + qr[f * 4 + 7] * k1.w;
          s2 += qr[f * 4 + 8] * k2.x + qr[f * 4 + 9] * k2.y + qr[f * 4 + 10] * k2.z + qr[f * 4 + 11] * k2.w;
          s3 += qr[f * 4 + 12] * k3.x + qr[f * 4 + 13] * k3.y + qr[f * 4 + 14] * k3.z + qr[f * 4 + 15] * k3.w;
        }
        s = (s0 + s1) + (s2 + s3);
      }
      sl[tt] = s;
    }
    float tm = sl[0];
#pragma unroll
    for (int tt = 1; tt < 9; ++tt) tm = fmaxf(tm, sl[tt]);
    const float mnew = fmaxf(mloc, tm);
    const float alpha = __builtin_amdgcn_exp2f(mloc - mnew);
    mloc = mnew;
    lloc *= alpha;
#pragma unroll
    for (int d = 0; d < 32; ++d) acc[d] *= alpha;
#pragma unroll
    for (int tt = 0; tt < 9; ++tt) {
      const int ni = pi + tt / 3 - 1;
      const int nj = pj + tt % 3 - 1;
      const bool ok = (ni >= 0) && (ni < 32) && (nj >= 0) && (nj < 32);
      if (ok) {
        const float p = __builtin_amdgcn_exp2f(sl[tt] - mnew);
        lloc += p;
        const float4* vr = (const float4*)(vlp + (kvbase + ni * 32 + nj) * 32);
#pragma unroll
        for (int f = 0; f < 8; ++f) {
          float4 vv = vr[f];
          acc[f * 4 + 0] += p * vv.x; acc[f * 4 + 1] += p * vv.y;
          acc[f * 4 + 2] += p * vv.z; acc[f * 4 + 3] += p * vv.w;
        }
      }
    }
  }

  // merge the 4 split-K partials (online-softmax identity) via LDS
  {
    float* cb = smem + (size_t)(w * 64 + lane) * 35;
    cb[0] = mloc;
    cb[1] = lloc;
#pragma unroll
    for (int d = 0; d < 32; ++d) cb[2 + d] = acc[d];
  }
  __syncthreads();
  if (w == 0) {
    float M = -1e30f, L = 0.f, A[32];
#pragma unroll
    for (int d = 0; d < 32; ++d) A[d] = 0.f;
#pragma unroll
    for (int ww = 0; ww < 4; ++ww) {
      const float* cb = smem + (size_t)(ww * 64 + lane) * 35;
      const float mw = cb[0], lw = cb[1];
      const float Mn = fmaxf(M, mw);
      const float a1 = __builtin_amdgcn_exp2f(M - Mn);
      const float a2 = __builtin_amdgcn_exp2f(mw - Mn);
      L = L * a1 + lw * a2;
#pragma unroll
      for (int d = 0; d < 32; ++d) A[d] = A[d] * a1 + cb[2 + d] * a2;
      M = Mn;
    }
    const float inv = 1.0f / L;
    const int bt = bth >> 3, head = bth & 7;
    float* op = ctx + (((size_t)bt * 1024 + n) * 8 + head) * 32;
#pragma unroll
    for (int f = 0; f < 8; ++f) {
      float4 o;
      o.x = A[f * 4 + 0] * inv; o.y = A[f * 4 + 1] * inv;
      o.z = A[f * 4 + 2] * inv; o.w = A[f * 4 + 3] * inv;
      ((float4*)op)[f] = o;
    }
  }
}

// ---------------------------------------------------------------------------
// K4: out = ctx(8192x256) @ Wo^T, stored as (B, D, T, H*W) with n contiguous.
// ---------------------------------------------------------------------------
__global__ __launch_bounds__(256) void outproj_kernel(const float* __restrict__ ctx,
                                                      const float* __restrict__ Wo,
                                                      float* __restrict__ out) {
  __shared__ float As[16][68];
  __shared__ float Bs[16][68];
  const int m0 = blockIdx.x * 64;
  const int o0 = blockIdx.y * 64;
  const int tid = threadIdx.x;
  const int tx = tid & 15, ty = tid >> 4;
  float c[4][4] = {};
#pragma unroll 1
  for (int k0 = 0; k0 < 256; k0 += 16) {
    const int kb = tid & 15, rb = tid >> 4;
#pragma unroll
    for (int r = 0; r < 4; ++r) {
      As[kb][rb + r * 16] = ctx[(size_t)(m0 + rb + r * 16) * 256 + k0 + kb];
      Bs[kb][rb + r * 16] = Wo[(size_t)(o0 + rb + r * 16) * 256 + k0 + kb];
    }
    __syncthreads();
#pragma unroll
    for (int kk = 0; kk < 16; ++kk) {
      const float4 a4 = *(const float4*)&As[kk][tx * 4];
      const float4 b4 = *(const float4*)&Bs[kk][ty * 4];
      const float a[4] = {a4.x, a4.y, a4.z, a4.w};
      const float b[4] = {b4.x, b4.y, b4.z, b4.w};
#pragma unroll
      for (int i = 0; i < 4; ++i)
#pragma unroll
        for (int j = 0; j < 4; ++j) c[i][j] += a[i] * b[j];
    }
    __syncthreads();
  }
#pragma unroll
  for (int i = 0; i < 4; ++i) {
    const int m = m0 + tx * 4 + i;
    const int bt = m >> 10, n = m & 1023;
    const int b = bt >> 2, t = bt & 3;
#pragma unroll
    for (int j = 0; j < 4; ++j) {
      const int o = o0 + ty * 4 + j;
      out[((size_t)(b * 256 + o) * 4 + t) * 1024 + n] = c[i][j];
    }
  }
}

extern "C" void kernel_launch(void* const* d_in, const int* in_sizes, int n_in,
                              void* d_out, int out_size, void* d_ws, size_t ws_size,
                              hipStream_t stream) {
  const float* x = (const float*)d_in[0];
  const float* gamma = (const float*)d_in[1];
  const float* beta = (const float*)d_in[2];
  const float* Wq = (const float*)d_in[3];
  const float* Wk = (const float*)d_in[4];
  const float* Wv = (const float*)d_in[5];
  const float* Wkl = (const float*)d_in[6];
  const float* Wvl = (const float*)d_in[7];
  const float* Wo = (const float*)d_in[8];
  const float* qb = (const float*)d_in[9];

  float* ws = (float*)d_ws;
  const size_t SZ = (size_t)NROWS * 256;  // 2M floats = 8 MB
  float* xnT = ws;
  float* q = ws + SZ;
  float* k = ws + 2 * SZ;
  float* v = ws + 3 * SZ;
  float* kl = ws + 4 * SZ;
  float* vl = ws + 5 * SZ;
  float* ctx = ws + 6 * SZ;

  hipLaunchKernelGGL(ln_kernel, dim3(128), dim3(256), 0, stream, x, gamma, beta, xnT);
  hipLaunchKernelGGL(proj_kernel, dim3(128, 4, 5), dim3(256), 0, stream, xnT, Wq,
                     Wk, Wv, Wkl, Wvl, qb, q, k, v, kl, vl);
  hipLaunchKernelGGL(attn_kernel, dim3(16, 64), dim3(256), 0, stream, q, k, v, kl,
                     vl, ctx);
  hipLaunchKernelGGL(outproj_kernel, dim3(128, 4), dim3(256), 0, stream, ctx, Wo,
                     (float*)d_out);
}

// Round 4
// 313.751 us; speedup vs baseline: 2.2807x; 2.2807x over previous
//
#include <hip/hip_runtime.h>

#define NROWS 8192  // BT * N = 8 * 1024

typedef float f32x4 __attribute__((ext_vector_type(4)));
typedef __bf16 bf16x8 __attribute__((ext_vector_type(8)));

// ---------------------------------------------------------------------------
// K1: LayerNorm over D=256 + transpose to K-major xnT[d][bt*1024+n]
// ---------------------------------------------------------------------------
__global__ __launch_bounds__(256) void ln_kernel(const float* __restrict__ x,
                                                 const float* __restrict__ gamma,
                                                 const float* __restrict__ beta,
                                                 float* __restrict__ xnT) {
  __shared__ float red[2][4][64];
  const int blk = blockIdx.x;  // 128 = bt(8) x nchunk(16)
  const int bt = blk >> 4;
  const int b = bt >> 2, t = bt & 3;
  const int n0 = (blk & 15) << 6;
  const int part = threadIdx.x >> 6, r = threadIdx.x & 63;
  const int n = n0 + r;
  const float* xp = x + ((size_t)(b * 256) * 4 + t) * 1024 + n;  // d stride 4096
  float sum = 0.f, sumsq = 0.f;
#pragma unroll 8
  for (int dd = 0; dd < 64; ++dd) {
    float vv = xp[(size_t)(part * 64 + dd) * 4096];
    sum += vv;
    sumsq += vv * vv;
  }
  red[0][part][r] = sum;
  red[1][part][r] = sumsq;
  __syncthreads();
  const float s1 = red[0][0][r] + red[0][1][r] + red[0][2][r] + red[0][3][r];
  const float s2 = red[1][0][r] + red[1][1][r] + red[1][2][r] + red[1][3][r];
  const float mu = s1 * (1.0f / 256.0f);
  const float var = s2 * (1.0f / 256.0f) - mu * mu;
  const float rstd = rsqrtf(var + 1e-6f);
  float* outp = xnT + (size_t)bt * 1024 + n;
#pragma unroll 8
  for (int dd = 0; dd < 64; ++dd) {
    const int d = part * 64 + dd;
    float vv = xp[(size_t)d * 4096];
    outp[(size_t)d * NROWS] = (vv - mu) * rstd * gamma[d] + beta[d];
  }
}

// ---------------------------------------------------------------------------
// K2: 5 projections fused via grid.z. C[m][o] = sum_d xnT[d][m] * W[o][d].
// Epilogue: z=0 q -> fp32 + bf16 hi/lo split; z=1 k -> hi/lo split;
// z=2 v -> TRANSPOSED ([dim][n]) hi/lo split; z=3/4 local k/v fp32.
// ---------------------------------------------------------------------------
__global__ __launch_bounds__(256) void proj_kernel(
    const float* __restrict__ xnT,
    const float* __restrict__ Wq, const float* __restrict__ Wk,
    const float* __restrict__ Wv, const float* __restrict__ Wkl,
    const float* __restrict__ Wvl, const float* __restrict__ qb,
    float* __restrict__ qf, __bf16* __restrict__ qh_g, __bf16* __restrict__ ql_g,
    __bf16* __restrict__ kh_g, __bf16* __restrict__ kl_g,
    __bf16* __restrict__ vhT_g, __bf16* __restrict__ vlT_g,
    float* __restrict__ kloc, float* __restrict__ vloc) {
  __shared__ float As[16][64];
  __shared__ float Bs[16][68];
  const int z = blockIdx.z;
  const float* Wm = (z == 0) ? Wq : (z == 1) ? Wk : (z == 2) ? Wv : (z == 3) ? Wkl : Wvl;
  const int m0 = blockIdx.x * 64;
  const int o0 = blockIdx.y * 64;
  const int tid = threadIdx.x;
  const int tx = tid & 15, ty = tid >> 4;
  float c[4][4] = {};
#pragma unroll 1
  for (int k0 = 0; k0 < 256; k0 += 16) {
    const int ml = tid & 63, kl4 = tid >> 6;
#pragma unroll
    for (int r = 0; r < 4; ++r)
      As[kl4 + r * 4][ml] = xnT[(size_t)(k0 + kl4 + r * 4) * NROWS + m0 + ml];
    const int kb = tid & 15, ob = tid >> 4;
#pragma unroll
    for (int r = 0; r < 4; ++r)
      Bs[kb][ob + r * 16] = Wm[(size_t)(o0 + ob + r * 16) * 256 + k0 + kb];
    __syncthreads();
#pragma unroll
    for (int kk = 0; kk < 16; ++kk) {
      const float4 a4 = *(const float4*)&As[kk][tx * 4];
      const float4 b4 = *(const float4*)&Bs[kk][ty * 4];
      const float a[4] = {a4.x, a4.y, a4.z, a4.w};
      const float b[4] = {b4.x, b4.y, b4.z, b4.w};
#pragma unroll
      for (int i = 0; i < 4; ++i)
#pragma unroll
        for (int j = 0; j < 4; ++j) c[i][j] += a[i] * b[j];
    }
    __syncthreads();
  }
#pragma unroll
  for (int i = 0; i < 4; ++i) {
    const int m = m0 + tx * 4 + i;
    const int bt = m >> 10, n = m & 1023;
#pragma unroll
    for (int j = 0; j < 4; ++j) {
      const int o = o0 + ty * 4 + j;
      float val = c[i][j];
      const int bth = bt * 8 + (o >> 5), dh = o & 31;
      const size_t idx = ((size_t)bth * 1024 + n) * 32 + dh;
      if (z == 0) {
        val += qb[o];
        qf[idx] = val;
        __bf16 h = (__bf16)val;
        qh_g[idx] = h;
        ql_g[idx] = (__bf16)(val - (float)h);
      } else if (z == 1) {
        __bf16 h = (__bf16)val;
        kh_g[idx] = h;
        kl_g[idx] = (__bf16)(val - (float)h);
      } else if (z == 2) {
        const size_t tix = ((size_t)bth * 32 + dh) * 1024 + n;
        __bf16 h = (__bf16)val;
        vhT_g[tix] = h;
        vlT_g[tix] = (__bf16)(val - (float)h);
      } else if (z == 3) {
        kloc[idx] = val;
      } else {
        vloc[idx] = val;
      }
    }
  }
}

// ---------------------------------------------------------------------------
// K3: MFMA flash attention (bf16x3 split arithmetic, fp32 accumulate).
// Block: 4 waves; wave w owns 16 queries (M=16); loop 32-key chunks.
// QK^T: A=Q frag (m=lane&15, k=8*(lane>>4)+j), B=K (n=key=lane&15, k=dim).
// C layout: col=lane&15, row=4*(lane>>4)+reg. PV via LDS P round-trip.
// 3x3 local part: fp32 VALU on wave 0 at the end (1% of work).
// ---------------------------------------------------------------------------
#define LSTRIDE 40  // bf16 elems per LDS tile row (32 + 8 pad; rows 16B-aligned)
__device__ __forceinline__ float rmax16(float v) {
  v = fmaxf(v, __shfl_xor(v, 1));
  v = fmaxf(v, __shfl_xor(v, 2));
  v = fmaxf(v, __shfl_xor(v, 4));
  v = fmaxf(v, __shfl_xor(v, 8));
  return v;
}
__device__ __forceinline__ float rsum16(float v) {
  v += __shfl_xor(v, 1);
  v += __shfl_xor(v, 2);
  v += __shfl_xor(v, 4);
  v += __shfl_xor(v, 8);
  return v;
}

__global__ __launch_bounds__(256) void attn_kernel(
    const __bf16* __restrict__ qh_g, const __bf16* __restrict__ ql_g,
    const __bf16* __restrict__ kh_g, const __bf16* __restrict__ kl_g,
    const __bf16* __restrict__ vhT_g, const __bf16* __restrict__ vlT_g,
    const float* __restrict__ qf, const float* __restrict__ kloc,
    const float* __restrict__ vloc, float* __restrict__ ctx) {
  __shared__ float smemf[2560];       // 10240B: staging tiles; epilogue obuf overlay
  __shared__ float pbuf[4][16 * 36];  // per-wave P round-trip (9216B)
  __bf16* khs = (__bf16*)smemf;
  __bf16* kls = khs + 32 * LSTRIDE;
  __bf16* vhs = khs + 64 * LSTRIDE;
  __bf16* vls = khs + 96 * LSTRIDE;
  float* obuf = smemf;  // 64*36 = 2304 floats

  const int qt = blockIdx.x, bth = blockIdx.y;
  const int tid = threadIdx.x;
  const int w = tid >> 6, lane = tid & 63;
  const int col = lane & 15, grp = lane >> 4;
  const int m0 = qt * 64 + w * 16;
  const float SCALE2 = 0.17677669529663687f * 1.4426950408889634f;  // dh^-.5*log2e
  const size_t kvbase = (size_t)bth << 10;

  // Q A-fragments (hi/lo)
  const bf16x8 qhf = *(const bf16x8*)(qh_g + (kvbase + m0 + col) * 32 + 8 * grp);
  const bf16x8 qlf = *(const bf16x8*)(ql_g + (kvbase + m0 + col) * 32 + 8 * grp);

  f32x4 oc0 = {0.f, 0.f, 0.f, 0.f}, oc1 = {0.f, 0.f, 0.f, 0.f};
  float mrow[4] = {-1e30f, -1e30f, -1e30f, -1e30f};
  float lrow[4] = {0.f, 0.f, 0.f, 0.f};

  const int skey = tid >> 3, sseg = tid & 7;  // staging: 32 rows x 8 x 8B
  float* pb = pbuf[w];

#pragma unroll 1
  for (int ch = 0; ch < 32; ++ch) {
    const int key0 = ch * 32;
    __syncthreads();
    {
      const uint2 a = *(const uint2*)(kh_g + (kvbase + key0 + skey) * 32 + sseg * 4);
      const uint2 b = *(const uint2*)(kl_g + (kvbase + key0 + skey) * 32 + sseg * 4);
      const uint2 cc = *(const uint2*)(vhT_g + ((size_t)bth * 32 + skey) * 1024 + key0 + sseg * 4);
      const uint2 d = *(const uint2*)(vlT_g + ((size_t)bth * 32 + skey) * 1024 + key0 + sseg * 4);
      *(uint2*)(khs + skey * LSTRIDE + sseg * 4) = a;
      *(uint2*)(kls + skey * LSTRIDE + sseg * 4) = b;
      *(uint2*)(vhs + skey * LSTRIDE + sseg * 4) = cc;
      *(uint2*)(vls + skey * LSTRIDE + sseg * 4) = d;
    }
    __syncthreads();
    // ---- QK^T (two 16-key col tiles, bf16x3 chained into one accumulator)
    const bf16x8 kh0 = *(const bf16x8*)(khs + col * LSTRIDE + 8 * grp);
    const bf16x8 kh1 = *(const bf16x8*)(khs + (16 + col) * LSTRIDE + 8 * grp);
    const bf16x8 kl0 = *(const bf16x8*)(kls + col * LSTRIDE + 8 * grp);
    const bf16x8 kl1 = *(const bf16x8*)(kls + (16 + col) * LSTRIDE + 8 * grp);
    f32x4 s0 = {0.f, 0.f, 0.f, 0.f}, s1 = {0.f, 0.f, 0.f, 0.f};
    s0 = __builtin_amdgcn_mfma_f32_16x16x32_bf16(qlf, kh0, s0, 0, 0, 0);
    s0 = __builtin_amdgcn_mfma_f32_16x16x32_bf16(qhf, kl0, s0, 0, 0, 0);
    s0 = __builtin_amdgcn_mfma_f32_16x16x32_bf16(qhf, kh0, s0, 0, 0, 0);
    s1 = __builtin_amdgcn_mfma_f32_16x16x32_bf16(qlf, kh1, s1, 0, 0, 0);
    s1 = __builtin_amdgcn_mfma_f32_16x16x32_bf16(qhf, kl1, s1, 0, 0, 0);
    s1 = __builtin_amdgcn_mfma_f32_16x16x32_bf16(qhf, kh1, s1, 0, 0, 0);
    // ---- online softmax per owned row r (row = 4*grp + r)
#pragma unroll
    for (int r = 0; r < 4; ++r) {
      const float sa = s0[r] * SCALE2, sb = s1[r] * SCALE2;
      const float mm = rmax16(fmaxf(sa, sb));
      const float mn = fmaxf(mrow[r], mm);
      const float al = __builtin_amdgcn_exp2f(mrow[r] - mn);
      mrow[r] = mn;
      const float p0 = __builtin_amdgcn_exp2f(sa - mn);
      const float p1 = __builtin_amdgcn_exp2f(sb - mn);
      lrow[r] = lrow[r] * al + rsum16(p0 + p1);
      oc0[r] *= al;
      oc1[r] *= al;
      pb[(grp * 4 + r) * 36 + col] = p0;
      pb[(grp * 4 + r) * 36 + 16 + col] = p1;
    }
    __builtin_amdgcn_wave_barrier();
    // ---- P: C-layout -> A-layout via wave-private LDS, split hi/lo bf16
    const f32x4 pa0 = *(const f32x4*)&pb[col * 36 + 8 * grp];
    const f32x4 pa1 = *(const f32x4*)&pb[col * 36 + 8 * grp + 4];
    bf16x8 ph, pl;
#pragma unroll
    for (int j = 0; j < 4; ++j) {
      const float pv = pa0[j];
      const __bf16 h = (__bf16)pv;
      ph[j] = h;
      pl[j] = (__bf16)(pv - (float)h);
    }
#pragma unroll
    for (int j = 0; j < 4; ++j) {
      const float pv = pa1[j];
      const __bf16 h = (__bf16)pv;
      ph[4 + j] = h;
      pl[4 + j] = (__bf16)(pv - (float)h);
    }
    // ---- PV (two 16-dim halves, bf16x3)
    const bf16x8 vh0 = *(const bf16x8*)(vhs + col * LSTRIDE + 8 * grp);
    const bf16x8 vh1 = *(const bf16x8*)(vhs + (16 + col) * LSTRIDE + 8 * grp);
    const bf16x8 vl0 = *(const bf16x8*)(vls + col * LSTRIDE + 8 * grp);
    const bf16x8 vl1 = *(const bf16x8*)(vls + (16 + col) * LSTRIDE + 8 * grp);
    oc0 = __builtin_amdgcn_mfma_f32_16x16x32_bf16(pl, vh0, oc0, 0, 0, 0);
    oc0 = __builtin_amdgcn_mfma_f32_16x16x32_bf16(ph, vl0, oc0, 0, 0, 0);
    oc0 = __builtin_amdgcn_mfma_f32_16x16x32_bf16(ph, vh0, oc0, 0, 0, 0);
    oc1 = __builtin_amdgcn_mfma_f32_16x16x32_bf16(pl, vh1, oc1, 0, 0, 0);
    oc1 = __builtin_amdgcn_mfma_f32_16x16x32_bf16(ph, vl1, oc1, 0, 0, 0);
    oc1 = __builtin_amdgcn_mfma_f32_16x16x32_bf16(ph, vh1, oc1, 0, 0, 0);
  }

  // ---- dump per-query state (O, m, l) to LDS; overlay on staging buffers
  __syncthreads();
#pragma unroll
  for (int r = 0; r < 4; ++r) {
    const int qq = w * 16 + grp * 4 + r;
    obuf[qq * 36 + col] = oc0[r];
    obuf[qq * 36 + 16 + col] = oc1[r];
    if (col == 0) {
      obuf[qq * 36 + 32] = mrow[r];
      obuf[qq * 36 + 33] = lrow[r];
    }
  }
  __syncthreads();

  // ---- local 3x3 pass + finalize: 64 lanes, lane = query (fp32 VALU)
  if (tid < 64) {
    const int qq = tid;
    const int n = qt * 64 + qq;
    float M = obuf[qq * 36 + 32], L = obuf[qq * 36 + 33];
    float A[32];
#pragma unroll
    for (int d = 0; d < 32; ++d) A[d] = obuf[qq * 36 + d];
    float qrf[32];
    {
      const float* qp = qf + (kvbase + n) * 32;
#pragma unroll
      for (int d = 0; d < 32; ++d) qrf[d] = qp[d] * SCALE2;
    }
    const int pi = n >> 5, pj = n & 31;
    float sl[9];
#pragma unroll
    for (int tt = 0; tt < 9; ++tt) {
      const int ni = pi + tt / 3 - 1;
      const int nj = pj + tt % 3 - 1;
      const bool ok = (ni >= 0) && (ni < 32) && (nj >= 0) && (nj < 32);
      float s = -1e30f;
      if (ok) {
        const float* kr = kloc + (kvbase + ni * 32 + nj) * 32;
        float s0 = 0.f, s1 = 0.f, s2 = 0.f, s3 = 0.f;
#pragma unroll
        for (int d = 0; d < 32; d += 4) {
          s0 = fmaf(qrf[d + 0], kr[d + 0], s0);
          s1 = fmaf(qrf[d + 1], kr[d + 1], s1);
          s2 = fmaf(qrf[d + 2], kr[d + 2], s2);
          s3 = fmaf(qrf[d + 3], kr[d + 3], s3);
        }
        s = (s0 + s1) + (s2 + s3);
      }
      sl[tt] = s;
    }
    float tm = sl[0];
#pragma unroll
    for (int tt = 1; tt < 9; ++tt) tm = fmaxf(tm, sl[tt]);
    const float mn = fmaxf(M, tm);
    const float al = __builtin_amdgcn_exp2f(M - mn);
    M = mn;
    L *= al;
#pragma unroll
    for (int d = 0; d < 32; ++d) A[d] *= al;
#pragma unroll
    for (int tt = 0; tt < 9; ++tt) {
      const int ni = pi + tt / 3 - 1;
      const int nj = pj + tt % 3 - 1;
      const bool ok = (ni >= 0) && (ni < 32) && (nj >= 0) && (nj < 32);
      if (ok) {
        const float p = __builtin_amdgcn_exp2f(sl[tt] - mn);
        L += p;
        const float* vr = vloc + (kvbase + ni * 32 + nj) * 32;
#pragma unroll
        for (int d = 0; d < 32; ++d) A[d] = fmaf(p, vr[d], A[d]);
      }
    }
    const float inv = 1.0f / L;
    const int bt = bth >> 3, head = bth & 7;
    float* op = ctx + (((size_t)bt * 1024 + n) * 8 + head) * 32;
#pragma unroll
    for (int f = 0; f < 8; ++f) {
      float4 o;
      o.x = A[f * 4 + 0] * inv;
      o.y = A[f * 4 + 1] * inv;
      o.z = A[f * 4 + 2] * inv;
      o.w = A[f * 4 + 3] * inv;
      ((float4*)op)[f] = o;
    }
  }
}

// ---------------------------------------------------------------------------
// K4: out = ctx(8192x256) @ Wo^T, stored as (B, D, T, H*W) with n contiguous.
// ---------------------------------------------------------------------------
__global__ __launch_bounds__(256) void outproj_kernel(const float* __restrict__ ctx,
                                                      const float* __restrict__ Wo,
                                                      float* __restrict__ out) {
  __shared__ float As[16][68];
  __shared__ float Bs[16][68];
  const int m0 = blockIdx.x * 64;
  const int o0 = blockIdx.y * 64;
  const int tid = threadIdx.x;
  const int tx = tid & 15, ty = tid >> 4;
  float c[4][4] = {};
#pragma unroll 1
  for (int k0 = 0; k0 < 256; k0 += 16) {
    const int kb = tid & 15, rb = tid >> 4;
#pragma unroll
    for (int r = 0; r < 4; ++r) {
      As[kb][rb + r * 16] = ctx[(size_t)(m0 + rb + r * 16) * 256 + k0 + kb];
      Bs[kb][rb + r * 16] = Wo[(size_t)(o0 + rb + r * 16) * 256 + k0 + kb];
    }
    __syncthreads();
#pragma unroll
    for (int kk = 0; kk < 16; ++kk) {
      const float4 a4 = *(const float4*)&As[kk][tx * 4];
      const float4 b4 = *(const float4*)&Bs[kk][ty * 4];
      const float a[4] = {a4.x, a4.y, a4.z, a4.w};
      const float b[4] = {b4.x, b4.y, b4.z, b4.w};
#pragma unroll
      for (int i = 0; i < 4; ++i)
#pragma unroll
        for (int j = 0; j < 4; ++j) c[i][j] += a[i] * b[j];
    }
    __syncthreads();
  }
#pragma unroll
  for (int i = 0; i < 4; ++i) {
    const int m = m0 + tx * 4 + i;
    const int bt = m >> 10, n = m & 1023;
    const int b = bt >> 2, t = bt & 3;
#pragma unroll
    for (int j = 0; j < 4; ++j) {
      const int o = o0 + ty * 4 + j;
      out[((size_t)(b * 256 + o) * 4 + t) * 1024 + n] = c[i][j];
    }
  }
}

extern "C" void kernel_launch(void* const* d_in, const int* in_sizes, int n_in,
                              void* d_out, int out_size, void* d_ws, size_t ws_size,
                              hipStream_t stream) {
  const float* x = (const float*)d_in[0];
  const float* gamma = (const float*)d_in[1];
  const float* beta = (const float*)d_in[2];
  const float* Wq = (const float*)d_in[3];
  const float* Wk = (const float*)d_in[4];
  const float* Wv = (const float*)d_in[5];
  const float* Wkl = (const float*)d_in[6];
  const float* Wvl = (const float*)d_in[7];
  const float* Wo = (const float*)d_in[8];
  const float* qb = (const float*)d_in[9];

  float* ws = (float*)d_ws;
  const size_t SZ = (size_t)NROWS * 256;  // 2M elems
  float* xnT = ws;
  float* qf = ws + SZ;
  float* kloc = ws + 2 * SZ;
  float* vloc = ws + 3 * SZ;
  float* ctx = ws + 4 * SZ;
  __bf16* bfb = (__bf16*)(ws + 5 * SZ);
  __bf16* qh = bfb;
  __bf16* ql = bfb + SZ;
  __bf16* kh = bfb + 2 * SZ;
  __bf16* kl = bfb + 3 * SZ;
  __bf16* vhT = bfb + 4 * SZ;
  __bf16* vlT = bfb + 5 * SZ;  // total ws: 20MB fp32 + 24MB bf16 = 44MB

  hipLaunchKernelGGL(ln_kernel, dim3(128), dim3(256), 0, stream, x, gamma, beta, xnT);
  hipLaunchKernelGGL(proj_kernel, dim3(128, 4, 5), dim3(256), 0, stream, xnT, Wq,
                     Wk, Wv, Wkl, Wvl, qb, qf, qh, ql, kh, kl, vhT, vlT, kloc, vloc);
  hipLaunchKernelGGL(attn_kernel, dim3(16, 64), dim3(256), 0, stream, qh, ql, kh,
                     kl, vhT, vlT, qf, kloc, vloc, ctx);
  hipLaunchKernelGGL(outproj_kernel, dim3(128, 4), dim3(256), 0, stream, ctx, Wo,
                     (float*)d_out);
}